// Round 14
// baseline (58.211 us; speedup 1.0000x reference)
//
#include <hip/hip_runtime.h>
#include <hip/hip_bf16.h>

// DivEncLayer via MFMA, R14: counted-vmcnt staging pipeline (T3/T4-minimal) with a
// pure-LDS compute phase.  per (b,q): z = W1^T x + b1; out = sum_h w2p*elu(z) + b2p.
//
// R13 -> R14: every prior pipeline was silently DRAINED: __syncthreads emits vmcnt(0)
// (R12), and in-loop global weight loads force the compiler to wait for the LAST-issued
// vmem op -- vmcnt retires in issue order, so that drains every older x prefetch (R13).
// Fix per the T4 recipe: (1) weights staged once per block into LDS (A 16KB + w2p 2KB +
// b2p 64B) so the K-loop has ZERO global loads -> the only vmcnt ops are my 2 stage
// instructions; (2) per chunk: raw s_barrier; stage(c+1); s_waitcnt vmcnt(2) (chunk c
// landed, c+1 stays in flight ACROSS the barrier); raw s_barrier; compute. vmcnt(0)
// only at the tail. Compute math/swizzle = R12 verbatim (verified, absmax 0.03125).
// LDS: 2x16K xbuf + 18.1K weights + 8.5K slab = 58.6KB -> 2 blocks/CU, 16 waves/CU.

#define QN 128
#define SN 8
#define HN 32
#define XROW 1024
#define BN_EPS 1e-3f
#define ROWS_BLK 128
#define CHUNK 32
#define QBLK 16

typedef short bf16x8 __attribute__((ext_vector_type(8)));
typedef float f32x16 __attribute__((ext_vector_type(16)));
typedef unsigned int u32;

typedef __attribute__((address_space(1))) void as1_void;
typedef __attribute__((address_space(3))) void as3_void;

#define WS_A_BYTES (QN * 64 * 16)                 // A[q][lane] 16B (b1 in hi-lane k8)
#define WS_W_OFF   WS_A_BYTES
#define WS_W_BYTES (QN * 32 * 4)                  // w2p[q][half*16+r] (f32, D-reg order)
#define WS_B2_OFF  (WS_W_OFF + WS_W_BYTES)        // b2p[q] (with -sum(w2p) folded)

// LDS layout (u32 units)
#define XB0   0                                    // x chunk buf 0 (4096)
#define XB1   4096                                 // x chunk buf 1 (4096)
#define LWA   8192                                 // A packs: 16 q x 1KB (4096)
#define LWW   12288                                // w2p: 16 q x 128B (512)
#define LB2   12800                                // b2p: 16 f32 (16)
#define LSLAB 12816                                // slab: 128 x 17 f32 (2176)
#define LDS_U32 (12816 + 128*17)                   // 14992 u32 = 58.6 KiB

static __device__ __forceinline__ u32 pkbf(float lo, float hi) {
    union { __hip_bfloat162 h2; u32 u; } c;
    c.h2 = __float22bfloat162_rn(float2{lo, hi});
    return c.u;
}

__global__ void divenc_prep(const float* __restrict__ W1, const float* __restrict__ b1,
                            const float* __restrict__ gamma_, const float* __restrict__ beta_,
                            const float* __restrict__ mmean, const float* __restrict__ mvar,
                            const float* __restrict__ W2, const float* __restrict__ b2,
                            unsigned char* __restrict__ ws)
{
    const int q = blockIdx.x;        // 0..127
    const int m = threadIdx.x;       // 0..63

    u32 d0 = 0, d1 = 0, d2 = 0, d3 = 0;
    if (m < 32) {                    // A[m][k0..7] = W1[q][k][m]
        d0 = pkbf(W1[(q*SN + 0)*HN + m], W1[(q*SN + 1)*HN + m]);
        d1 = pkbf(W1[(q*SN + 2)*HN + m], W1[(q*SN + 3)*HN + m]);
        d2 = pkbf(W1[(q*SN + 4)*HN + m], W1[(q*SN + 5)*HN + m]);
        d3 = pkbf(W1[(q*SN + 6)*HN + m], W1[(q*SN + 7)*HN + m]);
    } else {                         // A[m][k8] = b1[m] (bias; B k8 = 1.0), k9-15 = 0
        d0 = pkbf(b1[q*HN + (m - 32)], 0.f);
    }
    ((uint4*)ws)[q*64 + m] = uint4{d0, d1, d2, d3};

    float* wsW  = (float*)(ws + WS_W_OFF);
    float* wsB2 = (float*)(ws + WS_B2_OFF);
    if (m < 32) {                    // D-reg order: h = (r&3) + 8*(r>>2) + 4*half
        const int half = m >> 4, r = m & 15;
        const int h = (r & 3) + 8*(r >> 2) + 4*half;
        float inv = gamma_[q*HN+h] * rsqrtf(mvar[q*HN+h] + BN_EPS);
        wsW[q*32 + m] = inv * W2[q*HN + h];
    }
    if (m == 0) {
        float acc = b2[q];
        for (int h = 0; h < HN; ++h) {
            float inv = gamma_[q*HN+h] * rsqrtf(mvar[q*HN+h] + BN_EPS);
            float w2p = inv * W2[q*HN + h];
            acc += (beta_[q*HN+h] - mmean[q*HN+h]*inv) * W2[q*HN+h] - w2p;  // fold -sum(w2p)
        }
        wsB2[q] = acc;
    }
}

// Stage chunk c (32 rows x 512B): 16 instrs x 1KB contiguous; wave wv issues 2.
// Instr i covers rows {2i, 2i+1}; phys 16B-slot (lane&31) holds logical block (lane&31)^row
// (involution; read applies the same XOR). LDS dest linear (global_load_lds requirement).
__device__ __forceinline__
void stage_chunk(const float* __restrict__ x, u32* buf,
                 int b0, int q0, int c, int wv, int lane)
{
    #pragma unroll
    for (int k = 0; k < 2; ++k) {
        const int i  = wv * 2 + k;               // 0..15
        const int r  = i * 2 + (lane >> 5);      // chunk-local row 0..31
        const int jl = (lane & 31) ^ r;          // logical 16B-block index for phys slot
        const float* src = x + (size_t)(b0 + c * CHUNK + r) * XROW + q0 * SN + jl * 4;
        u32* dst = buf + i * 256;                // wave-uniform; HW adds lane*16B
        __builtin_amdgcn_global_load_lds((const as1_void*)src, (as3_void*)dst, 16, 0, 0);
    }
}

__global__ __launch_bounds__(512, 4)
void divenc_mfma(const float* __restrict__ x, const unsigned char* __restrict__ ws,
                 float* __restrict__ out)
{
    const int tid  = threadIdx.x;
    const int lane = tid & 63;
    const int wv   = tid >> 6;       // 0..7
    const int half = lane >> 5;
    const int bl   = lane & 31;
    const bool hi  = lane >= 32;
    const int b0   = blockIdx.x * ROWS_BLK;
    const int q0   = blockIdx.y * QBLK;

    __shared__ __align__(16) u32 smem[LDS_U32];

    // ---- prologue: stage weights (A, w2p, b2p) + x chunk 0.  All vmem issue order:
    // weights first, then stage(0) -> in-order retirement makes counted waits exact.
    #pragma unroll
    for (int k = 0; k < 2; ++k) {                 // A: 16 instrs x 1KB
        const int j = wv * 2 + k;                 // q-local 0..15
        const unsigned char* src = ws + (size_t)(q0 + j) * 1024 + lane * 16;
        __builtin_amdgcn_global_load_lds((const as1_void*)src,
                                         (as3_void*)(smem + LWA + j * 256), 16, 0, 0);
    }
    if (wv == 0 || wv == 1) {                     // w2p: 2 instrs x 1KB
        const unsigned char* src = ws + WS_W_OFF + (size_t)q0 * 128 + wv * 1024 + lane * 16;
        __builtin_amdgcn_global_load_lds((const as1_void*)src,
                                         (as3_void*)(smem + LWW + wv * 256), 16, 0, 0);
    }
    if (wv == 2 && lane < 16) {                   // b2p: 16 x 4B
        const unsigned char* src = ws + WS_B2_OFF + (size_t)q0 * 4 + lane * 4;
        __builtin_amdgcn_global_load_lds((const as1_void*)src,
                                         (as3_void*)(smem + LB2), 4, 0, 0);
    }
    stage_chunk(x, smem + XB0, b0, q0, 0, wv, lane);

    #pragma unroll 1
    for (int c = 0; c < 4; ++c) {
        asm volatile("s_barrier" ::: "memory");   // bar_A: compute(c-1) issued everywhere
        if (c < 3) {
            stage_chunk(x, smem + (((c + 1) & 1) ? XB1 : XB0), b0, q0, c + 1, wv, lane);
            asm volatile("s_waitcnt vmcnt(2)" ::: "memory");  // c landed; c+1 in flight
        } else {
            asm volatile("s_waitcnt vmcnt(0)" ::: "memory");  // tail drain
        }
        asm volatile("s_barrier" ::: "memory");   // bar_B: chunk c visible block-wide
        __builtin_amdgcn_sched_barrier(0);

        const u32* xb = smem + ((c & 1) ? XB1 : XB0);

        #pragma unroll
        for (int qg = 0; qg < 2; ++qg) {
            const int qloc = qg * 8 + wv;         // 0..15

            union { uint4 u; bf16x8 v; } A;       // LDS: 1KB stripe per q
            A.u = *(const uint4*)(smem + LWA + qloc * 256 + lane * 4);

            float w2r[16];                        // LDS broadcast (uniform per half)
            const float* wrp = (const float*)(smem + LWW) + qloc * 32 + half * 16;
            #pragma unroll
            for (int r = 0; r < 16; ++r) w2r[r] = wrp[r];
            const float b2p = ((const float*)(smem + LB2))[qloc];

            // lane's row bl: logical blocks 2qloc/2qloc+1 at phys = logical ^ bl
            const u32* rowp = xb + bl * 128;
            const uint4 xw0 = *(const uint4*)(rowp + (((2 * qloc)     ^ bl) * 4));
            const uint4 xw1 = *(const uint4*)(rowp + (((2 * qloc + 1) ^ bl) * 4));

            union { uint4 u; bf16x8 v; } B;       // hi: k8 = bf16(1.0) bias, k9-15 = 0
            B.u = uint4{
                hi ? 0x00003F80u : pkbf(__uint_as_float(xw0.x), __uint_as_float(xw0.y)),
                hi ? 0u          : pkbf(__uint_as_float(xw0.z), __uint_as_float(xw0.w)),
                hi ? 0u          : pkbf(__uint_as_float(xw1.x), __uint_as_float(xw1.y)),
                hi ? 0u          : pkbf(__uint_as_float(xw1.z), __uint_as_float(xw1.w)) };

            const f32x16 Z = {0.f,0.f,0.f,0.f,0.f,0.f,0.f,0.f,
                              0.f,0.f,0.f,0.f,0.f,0.f,0.f,0.f};
            f32x16 D = __builtin_amdgcn_mfma_f32_32x32x16_bf16(A.v, B.v, Z, 0, 0, 0);

            float p0 = 0.f, p1 = 0.f;             // elu = E + R - 1 (the -1 is in b2p)
            #pragma unroll
            for (int r = 0; r < 16; ++r) {
                const float z = D[r];
                const float E = __expf(fminf(z, 0.f));    // z>0 -> 1
                const float R = fmaxf(z, 0.f);
                p0 = fmaf(E, w2r[r], p0);
                p1 = fmaf(R, w2r[r], p1);
            }
            float p = p0 + p1;
            p += __shfl_xor(p, 32);               // combine h-halves (same b-col)
            if (!hi) ((float*)(smem + LSLAB))[(c * CHUNK + bl) * 17 + qloc] = p + b2p;
        }
    }

    __syncthreads();                              // slab complete (lgkm drained)

    // dump 128 rows x 16 q; 512 threads x 16B
    {
        const int row = tid >> 2;
        const int c4  = (tid & 3) * 4;
        const float* srow = (const float*)(smem + LSLAB) + row * 17 + c4;
        float4 vv;
        vv.x = srow[0]; vv.y = srow[1]; vv.z = srow[2]; vv.w = srow[3];
        *(float4*)(out + (size_t)(b0 + row) * QN + q0 + c4) = vv;
    }
}

extern "C" void kernel_launch(void* const* d_in, const int* in_sizes, int n_in,
                              void* d_out, int out_size, void* d_ws, size_t ws_size,
                              hipStream_t stream) {
    const float* x      = (const float*)d_in[0];
    const float* W1     = (const float*)d_in[1];
    const float* b1     = (const float*)d_in[2];
    const float* gamma_ = (const float*)d_in[3];
    const float* beta_  = (const float*)d_in[4];
    const float* mmean  = (const float*)d_in[5];
    const float* mvar   = (const float*)d_in[6];
    const float* W2     = (const float*)d_in[7];
    const float* b2     = (const float*)d_in[8];
    float* out = (float*)d_out;
    unsigned char* ws = (unsigned char*)d_ws;

    const int Btot = in_sizes[0] / XROW;              // 32768

    divenc_prep<<<QN, 64, 0, stream>>>(W1, b1, gamma_, beta_, mmean, mvar, W2, b2, ws);
    divenc_mfma<<<dim3(Btot / ROWS_BLK, QN / QBLK), 512, 0, stream>>>(x, ws, out);
}